// Round 1
// baseline (367.912 us; speedup 1.0000x reference)
//
#include <hip/hip_runtime.h>
#include <math.h>

#define BB 8
#define CC 64
#define HH 128
#define WW 128
#define HO 64
#define WO 128
#define OC 64

// ---------------------------------------------------------------------------
// Kernel 1: offset (18ch) + mask (9ch) conv, stride (2,1), pad (1,1).
// One thread per output position (b,h,w). 27 fp32 accumulators.
// Weight indices are wave-uniform -> compiler emits s_load (scalar path),
// x loads are coalesced across lanes (lane = w).
// Writes precomputed sample coords py/px and sigmoid(mask) to workspace.
// ---------------------------------------------------------------------------
__global__ __launch_bounds__(256) void om_conv(
    const float* __restrict__ x,
    const float* __restrict__ w_off, const float* __restrict__ b_off,
    const float* __restrict__ w_msk, const float* __restrict__ b_msk,
    float* __restrict__ py_out, float* __restrict__ px_out,
    float* __restrict__ m_out)
{
    int p = blockIdx.x * 256 + threadIdx.x;   // 65536 positions exactly
    int b = p >> 13;            // / (HO*WO)=8192
    int h = (p >> 7) & 63;
    int w = p & 127;
    int h2 = 2 * h - 1;         // input row of ky=0
    int wm1 = w - 1;            // input col of kx=0

    float acc[27];
#pragma unroll
    for (int co = 0; co < 27; ++co)
        acc[co] = (co < 18) ? b_off[co] : b_msk[co - 18];

    const float* xb = x + (size_t)b * (CC * HH * WW);
    for (int c = 0; c < CC; ++c) {
        const float* xc = xb + c * (HH * WW);
        float xp[9];
#pragma unroll
        for (int ky = 0; ky < 3; ++ky) {
            int hy = h2 + ky;
            bool rok = (unsigned)hy < (unsigned)HH;
#pragma unroll
            for (int kx = 0; kx < 3; ++kx) {
                int xw = wm1 + kx;
                bool ok = rok && ((unsigned)xw < (unsigned)WW);
                xp[ky * 3 + kx] = ok ? xc[hy * WW + xw] : 0.0f;
            }
        }
#pragma unroll
        for (int co = 0; co < 27; ++co) {
            const float* wb = (co < 18) ? (w_off + (co * CC + c) * 9)
                                        : (w_msk + ((co - 18) * CC + c) * 9);
            float s = acc[co];
#pragma unroll
            for (int k = 0; k < 9; ++k) s = fmaf(wb[k], xp[k], s);
            acc[co] = s;
        }
    }

    int base = ((b * 9) * HO + h) * WO + w;
#pragma unroll
    for (int k = 0; k < 9; ++k) {
        float offy = acc[2 * k];
        float offx = acc[2 * k + 1];
        float mk = 1.0f / (1.0f + __expf(-acc[18 + k]));
        py_out[base + k * HO * WO] = offy + (float)(k / 3) + (float)h2;
        px_out[base + k * HO * WO] = offx + (float)(k % 3) + (float)wm1;
        m_out [base + k * HO * WO] = mk;
    }
}

// ---------------------------------------------------------------------------
// Kernel 2: transpose w_conv (o,c,k) -> wT[k][c][o] so the main kernel's
// uniform weight reads are contiguous (s_load_dwordx16-friendly).
// ---------------------------------------------------------------------------
__global__ __launch_bounds__(256) void transpose_w(
    const float* __restrict__ w_conv, float* __restrict__ wT)
{
    int i = blockIdx.x * 256 + threadIdx.x;   // 36864 = 64*64*9 exactly
    int k = i % 9;
    int c = (i / 9) % CC;
    int o = i / (CC * 9);
    wT[(k * CC + c) * OC + o] = w_conv[i];
}

// ---------------------------------------------------------------------------
// Kernel 3: deformable sampling + output matvec.
// Thread = (position, half of the 64 out-channels). 32 accumulators.
// Per (k,c): 4 clamped gathers, bilinear weights (shared across channels,
// computed once per k), then 32 FMAs with wave-uniform weights (s_load).
// ---------------------------------------------------------------------------
__global__ __launch_bounds__(256) void dconv(
    const float* __restrict__ x,
    const float* __restrict__ py_in, const float* __restrict__ px_in,
    const float* __restrict__ m_in, const float* __restrict__ wT,
    float* __restrict__ out)
{
    int p = blockIdx.x * 256 + threadIdx.x;   // 65536 positions
    int o0 = blockIdx.y * 32;                 // out-channel half
    int b = p >> 13;
    int h = (p >> 7) & 63;
    int w = p & 127;

    float acc[32];
#pragma unroll
    for (int o = 0; o < 32; ++o) acc[o] = 0.0f;

    const float* xb = x + (size_t)b * (CC * HH * WW);

    for (int k = 0; k < 9; ++k) {
        int idx = ((b * 9 + k) * HO + h) * WO + w;
        float py = py_in[idx];
        float px = px_in[idx];
        float mk = m_in[idx];

        float y0f = floorf(py), x0f = floorf(px);
        float dy = py - y0f, dx = px - x0f;
        int y0 = (int)y0f, x0 = (int)x0f;
        int y1 = y0 + 1, x1 = x0 + 1;
        bool vy0 = (unsigned)y0 < (unsigned)HH;
        bool vy1 = (unsigned)y1 < (unsigned)HH;
        bool vx0 = (unsigned)x0 < (unsigned)WW;
        bool vx1 = (unsigned)x1 < (unsigned)WW;
        // fold mask + validity into the 4 corner weights
        float w00 = (1.0f - dy) * (1.0f - dx) * ((vy0 && vx0) ? mk : 0.0f);
        float w01 = (1.0f - dy) * dx          * ((vy0 && vx1) ? mk : 0.0f);
        float w10 = dy * (1.0f - dx)          * ((vy1 && vx0) ? mk : 0.0f);
        float w11 = dy * dx                   * ((vy1 && vx1) ? mk : 0.0f);
        int yc0 = min(max(y0, 0), HH - 1), yc1 = min(max(y1, 0), HH - 1);
        int xc0 = min(max(x0, 0), WW - 1), xc1 = min(max(x1, 0), WW - 1);
        int o00 = yc0 * WW + xc0, o01 = yc0 * WW + xc1;
        int o10 = yc1 * WW + xc0, o11 = yc1 * WW + xc1;

        const float* wk = wT + (k * CC) * OC + o0;
        for (int c = 0; c < CC; ++c) {
            const float* xc = xb + c * (HH * WW);
            float v = fmaf(w00, xc[o00],
                      fmaf(w01, xc[o01],
                      fmaf(w10, xc[o10], w11 * xc[o11])));
            const float* wc = wk + c * OC;   // 32 consecutive, wave-uniform
#pragma unroll
            for (int o = 0; o < 32; ++o) acc[o] = fmaf(wc[o], v, acc[o]);
        }
    }

    int ob = ((b * OC + o0) * HO + h) * WO + w;
#pragma unroll
    for (int o = 0; o < 32; ++o)
        out[ob + o * HO * WO] = acc[o];
}

// ---------------------------------------------------------------------------
extern "C" void kernel_launch(void* const* d_in, const int* in_sizes, int n_in,
                              void* d_out, int out_size, void* d_ws, size_t ws_size,
                              hipStream_t stream)
{
    const float* x      = (const float*)d_in[0];
    const float* w_off  = (const float*)d_in[1];
    const float* b_off  = (const float*)d_in[2];
    const float* w_msk  = (const float*)d_in[3];
    const float* b_msk  = (const float*)d_in[4];
    const float* w_conv = (const float*)d_in[5];
    float* out = (float*)d_out;

    const int NPM = BB * 9 * HO * WO;  // 589824 per array
    float* py = (float*)d_ws;
    float* px = py + NPM;
    float* m  = px + NPM;
    float* wT = m + NPM;               // 36864 floats

    om_conv<<<dim3(256), dim3(256), 0, stream>>>(x, w_off, b_off, w_msk, b_msk,
                                                 py, px, m);
    transpose_w<<<dim3(144), dim3(256), 0, stream>>>(w_conv, wT);
    dconv<<<dim3(256, 2), dim3(256), 0, stream>>>(x, py, px, m, wT, out);
}

// Round 3
// 342.970 us; speedup vs baseline: 1.0727x; 1.0727x over previous
//
#include <hip/hip_runtime.h>
#include <math.h>

#define BB 8
#define CC 64
#define HH 128
#define WW 128
#define HO 64
#define WO 128
#define OC 64
#define HW (HH * WW)

// ---------------------------------------------------------------------------
// Kernel 1: offset (18ch) + mask (9ch) conv, stride (2,1), pad (1,1).
// Block = 64 positions x 4 channel-chunks (chunk wave-uniform so weight
// reads stay s_load). 4096 waves total (16/CU). LDS reduce (pad 29 ->
// conflict-free), 64-thread epilogue writes py/px/sigmoid(mask).
// ---------------------------------------------------------------------------
__global__ __launch_bounds__(256) void om_conv(
    const float* __restrict__ x,
    const float* __restrict__ w_off, const float* __restrict__ b_off,
    const float* __restrict__ w_msk, const float* __restrict__ b_msk,
    float* __restrict__ py_out, float* __restrict__ px_out,
    float* __restrict__ m_out)
{
    __shared__ float red[4][64][29];   // pad 29: gcd(29,32)=1, conflict-free

    int tid = threadIdx.x;
    int lane = tid & 63;
    int chunk = __builtin_amdgcn_readfirstlane(tid >> 6);  // wave-uniform

    int p = blockIdx.x * 64 + lane;    // 1024 blocks * 64 = 65536 positions
    int b = p >> 13;
    int h = (p >> 7) & 63;
    int w = p & 127;
    int h2 = 2 * h - 1;
    int wm1 = w - 1;

    float acc[27];
#pragma unroll
    for (int co = 0; co < 27; ++co) acc[co] = 0.0f;

    const float* xb = x + (size_t)b * (CC * HW);
    for (int ci = 0; ci < 16; ++ci) {
        int c = chunk * 16 + ci;
        const float* xc = xb + c * HW;
        float xp[9];
#pragma unroll
        for (int ky = 0; ky < 3; ++ky) {
            int hy = h2 + ky;
            bool rok = (unsigned)hy < (unsigned)HH;
#pragma unroll
            for (int kx = 0; kx < 3; ++kx) {
                int xw = wm1 + kx;
                bool ok = rok && ((unsigned)xw < (unsigned)WW);
                xp[ky * 3 + kx] = ok ? xc[hy * WW + xw] : 0.0f;
            }
        }
#pragma unroll
        for (int co = 0; co < 27; ++co) {
            const float* wb = (co < 18) ? (w_off + (co * CC + c) * 9)
                                        : (w_msk + ((co - 18) * CC + c) * 9);
            float s = acc[co];
#pragma unroll
            for (int k = 0; k < 9; ++k) s = fmaf(wb[k], xp[k], s);
            acc[co] = s;
        }
    }

#pragma unroll
    for (int co = 0; co < 27; ++co) red[chunk][lane][co] = acc[co];
    __syncthreads();

    if (tid < 64) {
        float s[27];
#pragma unroll
        for (int co = 0; co < 27; ++co)
            s[co] = red[0][lane][co] + red[1][lane][co]
                  + red[2][lane][co] + red[3][lane][co];
        int base = ((b * 9) * HO + h) * WO + w;
#pragma unroll
        for (int k = 0; k < 9; ++k) {
            float offy = s[2 * k] + b_off[2 * k];
            float offx = s[2 * k + 1] + b_off[2 * k + 1];
            float mk = 1.0f / (1.0f + __expf(-(s[18 + k] + b_msk[k])));
            py_out[base + k * HO * WO] = offy + (float)(k / 3) + (float)h2;
            px_out[base + k * HO * WO] = offx + (float)(k % 3) + (float)wm1;
            m_out [base + k * HO * WO] = mk;
        }
    }
}

// ---------------------------------------------------------------------------
// Kernel 2: transpose w_conv (o,c,k) -> wT[k][c][o].
// ---------------------------------------------------------------------------
__global__ __launch_bounds__(256) void transpose_w(
    const float* __restrict__ w_conv, float* __restrict__ wT)
{
    int i = blockIdx.x * 256 + threadIdx.x;   // 36864 exactly
    int k = i % 9;
    int c = (i / 9) % CC;
    int o = i / (CC * 9);
    wT[(k * CC + c) * OC + o] = w_conv[i];
}

// ---------------------------------------------------------------------------
// Kernel 3: deformable sampling + output matvec.
// Block = 256 thr = 2 pos-groups x (wave = 64 positions, c-half wave-uniform).
// blockIdx.y = o-half. 4096 waves (16/CU). Gathers batched 4 channels at a
// time (16 independent loads in flight). Weights stay wave-uniform -> s_load.
// Cross-wave c-half reduction via LDS [pair][o][lane] (conflict-free).
// ---------------------------------------------------------------------------
__global__ __launch_bounds__(256) void dconv(
    const float* __restrict__ x,
    const float* __restrict__ py_in, const float* __restrict__ px_in,
    const float* __restrict__ m_in, const float* __restrict__ wT,
    float* __restrict__ out)
{
    __shared__ float red[2][32][64];   // 16 KB

    int tid = threadIdx.x;
    int lane = tid & 63;
    int wv = tid >> 6;
    int chalf = __builtin_amdgcn_readfirstlane(wv & 1);
    int pg    = __builtin_amdgcn_readfirstlane(wv >> 1);

    int p = blockIdx.x * 128 + pg * 64 + lane;  // 512 blocks * 128 = 65536
    int o0 = blockIdx.y * 32;
    int b = p >> 13;
    int h = (p >> 7) & 63;
    int w = p & 127;

    float acc[32];
#pragma unroll
    for (int o = 0; o < 32; ++o) acc[o] = 0.0f;

    const float* xc0 = x + (size_t)b * (CC * HW) + (chalf * 32) * HW;

    for (int k = 0; k < 9; ++k) {
        int idx = ((b * 9 + k) * HO + h) * WO + w;
        float py = py_in[idx];
        float px = px_in[idx];
        float mk = m_in[idx];

        float y0f = floorf(py), x0f = floorf(px);
        float dy = py - y0f, dx = px - x0f;
        int y0 = (int)y0f, x0 = (int)x0f;
        int y1 = y0 + 1, x1 = x0 + 1;
        bool vy0 = (unsigned)y0 < (unsigned)HH;
        bool vy1 = (unsigned)y1 < (unsigned)HH;
        bool vx0 = (unsigned)x0 < (unsigned)WW;
        bool vx1 = (unsigned)x1 < (unsigned)WW;
        float w00 = (1.0f - dy) * (1.0f - dx) * ((vy0 && vx0) ? mk : 0.0f);
        float w01 = (1.0f - dy) * dx          * ((vy0 && vx1) ? mk : 0.0f);
        float w10 = dy * (1.0f - dx)          * ((vy1 && vx0) ? mk : 0.0f);
        float w11 = dy * dx                   * ((vy1 && vx1) ? mk : 0.0f);
        int yc0 = min(max(y0, 0), HH - 1), yc1 = min(max(y1, 0), HH - 1);
        int xc0i = min(max(x0, 0), WW - 1), xc1i = min(max(x1, 0), WW - 1);
        int o00 = yc0 * WW + xc0i, o01 = yc0 * WW + xc1i;
        int o10 = yc1 * WW + xc0i, o11 = yc1 * WW + xc1i;

        const float* wk = wT + ((size_t)(k * CC + chalf * 32)) * OC + o0;

        for (int cc = 0; cc < 8; ++cc) {          // 4 channels per chunk
            float g[16];
#pragma unroll
            for (int j = 0; j < 4; ++j) {
                const float* xc = xc0 + (cc * 4 + j) * HW;
                g[4 * j + 0] = xc[o00];
                g[4 * j + 1] = xc[o01];
                g[4 * j + 2] = xc[o10];
                g[4 * j + 3] = xc[o11];
            }
#pragma unroll
            for (int j = 0; j < 4; ++j) {
                float v = fmaf(w00, g[4 * j + 0],
                          fmaf(w01, g[4 * j + 1],
                          fmaf(w10, g[4 * j + 2], w11 * g[4 * j + 3])));
                const float* wc = wk + (cc * 4 + j) * OC;  // wave-uniform
#pragma unroll
                for (int o = 0; o < 32; ++o) acc[o] = fmaf(wc[o], v, acc[o]);
            }
        }
    }

    // reduce the two c-halves (partner waves within the block)
    if (chalf == 0) {
#pragma unroll
        for (int o = 0; o < 32; ++o) red[pg][o][lane] = acc[o];
    }
    __syncthreads();
    if (chalf == 1) {
        int ob = ((b * OC + o0) * HO + h) * WO + w;
#pragma unroll
        for (int o = 0; o < 32; ++o)
            out[ob + o * HO * WO] = acc[o] + red[pg][o][lane];
    }
}

// ---------------------------------------------------------------------------
extern "C" void kernel_launch(void* const* d_in, const int* in_sizes, int n_in,
                              void* d_out, int out_size, void* d_ws, size_t ws_size,
                              hipStream_t stream)
{
    const float* x      = (const float*)d_in[0];
    const float* w_off  = (const float*)d_in[1];
    const float* b_off  = (const float*)d_in[2];
    const float* w_msk  = (const float*)d_in[3];
    const float* b_msk  = (const float*)d_in[4];
    const float* w_conv = (const float*)d_in[5];
    float* out = (float*)d_out;

    const int NPM = BB * 9 * HO * WO;  // 589824 per array
    float* py = (float*)d_ws;
    float* px = py + NPM;
    float* m  = px + NPM;
    float* wT = m + NPM;               // 36864 floats

    om_conv<<<dim3(1024), dim3(256), 0, stream>>>(x, w_off, b_off, w_msk, b_msk,
                                                  py, px, m);
    transpose_w<<<dim3(144), dim3(256), 0, stream>>>(w_conv, wT);
    dconv<<<dim3(512, 2), dim3(256), 0, stream>>>(x, py, px, m, wT, out);
}

// Round 4
// 240.047 us; speedup vs baseline: 1.5327x; 1.4288x over previous
//
#include <hip/hip_runtime.h>
#include <hip/hip_bf16.h>
#include <math.h>

#define BB 8
#define CC 64
#define HH 128
#define WW 128
#define HO 64
#define WO 128
#define OC 64
#define HW (HH * WW)

typedef __attribute__((ext_vector_type(8))) short short8;
typedef __attribute__((ext_vector_type(4))) float floatx4;

// ---------------------------------------------------------------------------
// Kernel 1: offset (18ch) + mask (9ch) conv, stride (2,1), pad (1,1).
// XCD swizzle: b = blockIdx.x & 7 -> each XCD works one batch (4.2MB ~ L2).
// Block = 64 positions x 4 channel-chunks (chunk wave-uniform -> s_load
// weights). Explicit patch pipeline (load c+1 while FMA-ing c).
// ---------------------------------------------------------------------------
__global__ __launch_bounds__(256) void om_conv(
    const float* __restrict__ x,
    const float* __restrict__ w_off, const float* __restrict__ b_off,
    const float* __restrict__ w_msk, const float* __restrict__ b_msk,
    float* __restrict__ py_out, float* __restrict__ px_out,
    float* __restrict__ m_out)
{
    __shared__ float red[4][64][29];   // pad 29 -> conflict-free

    int tid = threadIdx.x;
    int lane = tid & 63;
    int chunk = __builtin_amdgcn_readfirstlane(tid >> 6);

    int bx = blockIdx.x;               // 1024 blocks
    int b = bx & 7;                    // XCD-local batch
    int rest = bx >> 3;                // 128 = 64 h * 2 w-halves
    int h = rest >> 1;
    int w = (rest & 1) * 64 + lane;
    int h2 = 2 * h - 1;
    int wm1 = w - 1;

    float acc[27];
#pragma unroll
    for (int co = 0; co < 27; ++co) acc[co] = 0.0f;

    const float* xb = x + (size_t)b * (CC * HW);

    auto load_patch = [&](int c, float* xp) {
        const float* xc = xb + c * HW;
#pragma unroll
        for (int ky = 0; ky < 3; ++ky) {
            int hy = h2 + ky;
            bool rok = (unsigned)hy < (unsigned)HH;
#pragma unroll
            for (int kx = 0; kx < 3; ++kx) {
                int xw = wm1 + kx;
                bool ok = rok && ((unsigned)xw < (unsigned)WW);
                xp[ky * 3 + kx] = ok ? xc[hy * WW + xw] : 0.0f;
            }
        }
    };

    float xp[9], xq[9];
    load_patch(chunk * 16, xp);
    for (int ci = 0; ci < 16; ++ci) {
        int c = chunk * 16 + ci;
        if (ci < 15) load_patch(c + 1, xq);
#pragma unroll
        for (int co = 0; co < 27; ++co) {
            const float* wb = (co < 18) ? (w_off + (co * CC + c) * 9)
                                        : (w_msk + ((co - 18) * CC + c) * 9);
            float s = acc[co];
#pragma unroll
            for (int k = 0; k < 9; ++k) s = fmaf(wb[k], xp[k], s);
            acc[co] = s;
        }
#pragma unroll
        for (int k = 0; k < 9; ++k) xp[k] = xq[k];
    }

#pragma unroll
    for (int co = 0; co < 27; ++co) red[chunk][lane][co] = acc[co];
    __syncthreads();

    if (tid < 64) {
        float s[27];
#pragma unroll
        for (int co = 0; co < 27; ++co)
            s[co] = red[0][lane][co] + red[1][lane][co]
                  + red[2][lane][co] + red[3][lane][co];
        int base = ((b * 9) * HO + h) * WO + w;
#pragma unroll
        for (int k = 0; k < 9; ++k) {
            float offy = s[2 * k] + b_off[2 * k];
            float offx = s[2 * k + 1] + b_off[2 * k + 1];
            float mk = 1.0f / (1.0f + __expf(-(s[18 + k] + b_msk[k])));
            py_out[base + k * HO * WO] = offy + (float)(k / 3) + (float)h2;
            px_out[base + k * HO * WO] = offx + (float)(k % 3) + (float)wm1;
            m_out [base + k * HO * WO] = mk;
        }
    }
}

// ---------------------------------------------------------------------------
// Kernel 2: w_conv (o,c,k) fp32 -> W2[k][o][c] bf16 (A-operand friendly:
// 8 consecutive c per lane = 16B load).
// ---------------------------------------------------------------------------
__global__ __launch_bounds__(256) void make_w2(
    const float* __restrict__ w_conv, __hip_bfloat16* __restrict__ W2)
{
    int i = blockIdx.x * 256 + threadIdx.x;   // 36864 exactly
    int k = i % 9;
    int c = (i / 9) % CC;
    int o = i / (CC * 9);
    W2[((size_t)k * OC + o) * CC + c] = __float2bfloat16(w_conv[i]);
}

// ---------------------------------------------------------------------------
// Kernel 3: deformable sampling + MFMA matvec.
// Block = 256 thr = 4 waves, pos-tile = 64 (one b,h, half-row of w).
// Per k-tap: gather phase (thread = (pos=tid&63, 16 ch = (tid>>6)*16)) writes
// bf16 S[pos][c] tile to LDS with XOR c-block swizzle (conflict-free b128
// reads); MFMA phase: wave w owns o-tile [16w,16w+16), 2 K-steps x 4 N-tiles
// of mfma_f32_16x16x32_bf16. No o-duplication of gathers, fp32 accumulate.
// XCD swizzle: b = blockIdx.x & 7.
// ---------------------------------------------------------------------------
__global__ __launch_bounds__(256) void dconv_mfma(
    const float* __restrict__ x,
    const float* __restrict__ py_in, const float* __restrict__ px_in,
    const float* __restrict__ m_in,
    const __hip_bfloat16* __restrict__ W2,
    float* __restrict__ out)
{
    __shared__ __align__(16) __hip_bfloat16 S[64][64];  // 8 KB, [pos][c-swizzled]

    int tid = threadIdx.x;
    int lane = tid & 63;
    int wv = tid >> 6;

    int bx = blockIdx.x;               // 1024 blocks
    int b = bx & 7;
    int rest = bx >> 3;
    int h = rest >> 1;
    int w0 = (rest & 1) * 64;

    // gather role
    int gpos = lane;                   // position within tile
    int cg = wv;                       // channels cg*16 .. +16

    floatx4 acc[4];
#pragma unroll
    for (int nt = 0; nt < 4; ++nt) acc[nt] = (floatx4){0.f, 0.f, 0.f, 0.f};

    const float* xb = x + (size_t)b * (CC * HW);
    const int m16 = lane & 15;
    const int q = lane >> 4;

    for (int k = 0; k < 9; ++k) {
        // ---------------- gather phase ----------------
        int idx = ((b * 9 + k) * HO + h) * WO + w0 + gpos;
        float py = py_in[idx];
        float px = px_in[idx];
        float mk = m_in[idx];

        float y0f = floorf(py), x0f = floorf(px);
        float dy = py - y0f, dx = px - x0f;
        int y0 = (int)y0f, x0 = (int)x0f;
        int y1 = y0 + 1, x1 = x0 + 1;
        bool vy0 = (unsigned)y0 < (unsigned)HH;
        bool vy1 = (unsigned)y1 < (unsigned)HH;
        bool vx0 = (unsigned)x0 < (unsigned)WW;
        bool vx1 = (unsigned)x1 < (unsigned)WW;
        float w00 = (1.0f - dy) * (1.0f - dx) * ((vy0 && vx0) ? mk : 0.0f);
        float w01 = (1.0f - dy) * dx          * ((vy0 && vx1) ? mk : 0.0f);
        float w10 = dy * (1.0f - dx)          * ((vy1 && vx0) ? mk : 0.0f);
        float w11 = dy * dx                   * ((vy1 && vx1) ? mk : 0.0f);
        int yc0 = min(max(y0, 0), HH - 1), yc1 = min(max(y1, 0), HH - 1);
        int xc0i = min(max(x0, 0), WW - 1), xc1i = min(max(x1, 0), WW - 1);
        int o00 = yc0 * WW + xc0i, o01 = yc0 * WW + xc1i;
        int o10 = yc1 * WW + xc0i, o11 = yc1 * WW + xc1i;

        const float* xc = xb + (cg * 16) * HW;
#pragma unroll
        for (int j = 0; j < 16; j += 2) {
            const float* xa = xc + j * HW;
            const float* xd = xa + HW;
            float g0 = fmaf(w00, xa[o00], fmaf(w01, xa[o01],
                       fmaf(w10, xa[o10], w11 * xa[o11])));
            float g1 = fmaf(w00, xd[o00], fmaf(w01, xd[o01],
                       fmaf(w10, xd[o10], w11 * xd[o11])));
            // logical c = cg*16 + j ; swizzle c-blocks of 8 by pos&7
            int cb = cg * 2 + (j >> 3);
            int phys = (cb ^ (gpos & 7)) * 8 + (j & 7);
            __hip_bfloat162 pr;
            pr.x = __float2bfloat16(g0);
            pr.y = __float2bfloat16(g1);
            *(__hip_bfloat162*)&S[gpos][phys] = pr;
        }
        __syncthreads();

        // ---------------- MFMA phase ----------------
        const __hip_bfloat16* wk = W2 + ((size_t)k * OC + wv * 16 + m16) * CC;
#pragma unroll
        for (int s = 0; s < 2; ++s) {
            short8 afrag = *(const short8*)(wk + q * 8 + s * 32);
#pragma unroll
            for (int nt = 0; nt < 4; ++nt) {
                int pos = nt * 16 + m16;
                int phys = ((q + 4 * s) ^ (pos & 7)) * 8;
                short8 bfrag = *(const short8*)&S[pos][phys];
                acc[nt] = __builtin_amdgcn_mfma_f32_16x16x32_bf16(
                    afrag, bfrag, acc[nt], 0, 0, 0);
            }
        }
        __syncthreads();
    }

    // epilogue: C/D layout col=lane&15 (pos), row=(lane>>4)*4+reg (o)
#pragma unroll
    for (int nt = 0; nt < 4; ++nt) {
#pragma unroll
        for (int r = 0; r < 4; ++r) {
            int o = wv * 16 + q * 4 + r;
            int wout = w0 + nt * 16 + m16;
            out[(((size_t)b * OC + o) * HO + h) * WO + wout] = acc[nt][r];
        }
    }
}

// ---------------------------------------------------------------------------
extern "C" void kernel_launch(void* const* d_in, const int* in_sizes, int n_in,
                              void* d_out, int out_size, void* d_ws, size_t ws_size,
                              hipStream_t stream)
{
    const float* x      = (const float*)d_in[0];
    const float* w_off  = (const float*)d_in[1];
    const float* b_off  = (const float*)d_in[2];
    const float* w_msk  = (const float*)d_in[3];
    const float* b_msk  = (const float*)d_in[4];
    const float* w_conv = (const float*)d_in[5];
    float* out = (float*)d_out;

    const int NPM = BB * 9 * HO * WO;  // 589824 per array
    float* py = (float*)d_ws;
    float* px = py + NPM;
    float* m  = px + NPM;
    __hip_bfloat16* W2 = (__hip_bfloat16*)(m + NPM);  // 36864 bf16, 16B-aligned

    om_conv<<<dim3(1024), dim3(256), 0, stream>>>(x, w_off, b_off, w_msk, b_msk,
                                                  py, px, m);
    make_w2<<<dim3(144), dim3(256), 0, stream>>>(w_conv, W2);
    dconv_mfma<<<dim3(1024), dim3(256), 0, stream>>>(x, py, px, m, W2, out);
}

// Round 5
// 209.605 us; speedup vs baseline: 1.7553x; 1.1452x over previous
//
#include <hip/hip_runtime.h>
#include <hip/hip_bf16.h>
#include <math.h>

#define BB 8
#define CC 64
#define HH 128
#define WW 128
#define HO 64
#define WO 128
#define OC 64
#define HW (HH * WW)
#define NPM (BB * 9 * HO * WO)

typedef __attribute__((ext_vector_type(8))) short short8;
typedef __attribute__((ext_vector_type(4))) float floatx4;
typedef float float2v __attribute__((ext_vector_type(2)));
typedef float float2a __attribute__((ext_vector_type(2), aligned(4)));  // 8B load, 4B align ok

union BfBits { __hip_bfloat16 h; short s; };

// ---------------------------------------------------------------------------
// Prep A: w_off/w_msk -> w3[c][256] fp32 contiguous (co*9+k), for chunked
// s_load in om_conv.
// ---------------------------------------------------------------------------
__global__ __launch_bounds__(256) void make_w3(
    const float* __restrict__ w_off, const float* __restrict__ w_msk,
    float* __restrict__ w3)
{
    int i = blockIdx.x * 256 + threadIdx.x;   // 15552 = 27*64*9
    if (i >= 27 * CC * 9) return;
    int kk = i % 9;
    int c  = (i / 9) % CC;
    int co = i / (9 * CC);
    float v = (co < 18) ? w_off[(co * CC + c) * 9 + kk]
                        : w_msk[((co - 18) * CC + c) * 9 + kk];
    w3[c * 256 + co * 9 + kk] = v;
}

// ---------------------------------------------------------------------------
// Prep B: w_conv (o,c,k) fp32 -> W2[k][o][c] bf16 (MFMA A-operand layout).
// ---------------------------------------------------------------------------
__global__ __launch_bounds__(256) void make_w2(
    const float* __restrict__ w_conv, __hip_bfloat16* __restrict__ W2)
{
    int i = blockIdx.x * 256 + threadIdx.x;   // 36864 exactly
    int k = i % 9;
    int c = (i / 9) % CC;
    int o = i / (CC * 9);
    W2[((size_t)k * OC + o) * CC + c] = __float2bfloat16(w_conv[i]);
}

// ---------------------------------------------------------------------------
// Kernel 1: offset+mask conv. Unconditional clamped patch loads * 0/1 masks
// (no exec-mask predication), contiguous w3 weights, XCD swizzle b=bx&7,
// explicit channel pipeline. Writes packed (py,px) float2 + sigmoid(mask).
// ---------------------------------------------------------------------------
__global__ __launch_bounds__(256) void om_conv(
    const float* __restrict__ x, const float* __restrict__ w3,
    const float* __restrict__ b_off, const float* __restrict__ b_msk,
    float2v* __restrict__ pypx, float* __restrict__ m_out)
{
    __shared__ float red[4][64][29];   // pad 29 -> conflict-free

    int tid = threadIdx.x;
    int lane = tid & 63;
    int chunk = __builtin_amdgcn_readfirstlane(tid >> 6);

    int bx = blockIdx.x;               // 1024 blocks
    int b = bx & 7;
    int rest = bx >> 3;                // 128 = 64 h * 2 w-halves
    int h = rest >> 1;
    int w = (rest & 1) * 64 + lane;
    int h2 = 2 * h - 1;
    int wm1 = w - 1;

    // clamped patch indices + validity masks (per thread, once)
    int idx9[9];
    float msk9[9];
#pragma unroll
    for (int ky = 0; ky < 3; ++ky) {
        int hy = h2 + ky;
        int hyc = min(max(hy, 0), HH - 1);
        float my = ((unsigned)hy < (unsigned)HH) ? 1.0f : 0.0f;
#pragma unroll
        for (int kx = 0; kx < 3; ++kx) {
            int xw = wm1 + kx;
            int xwc = min(max(xw, 0), WW - 1);
            float mx = ((unsigned)xw < (unsigned)WW) ? 1.0f : 0.0f;
            idx9[ky * 3 + kx] = hyc * WW + xwc;
            msk9[ky * 3 + kx] = my * mx;
        }
    }

    float acc[27];
#pragma unroll
    for (int co = 0; co < 27; ++co) acc[co] = 0.0f;

    const float* xb = x + (size_t)b * (CC * HW) + (size_t)chunk * 16 * HW;

    float xp[9], xq[9];
#pragma unroll
    for (int k = 0; k < 9; ++k) xp[k] = xb[idx9[k]] * msk9[k];

    for (int ci = 0; ci < 16; ++ci) {
        if (ci < 15) {
            const float* xc = xb + (ci + 1) * HW;
#pragma unroll
            for (int k = 0; k < 9; ++k) xq[k] = xc[idx9[k]];
        }
        int c = chunk * 16 + ci;
        const float* wc = w3 + c * 256;     // wave-uniform -> s_load
#pragma unroll
        for (int co = 0; co < 27; ++co) {
            float s = acc[co];
#pragma unroll
            for (int k = 0; k < 9; ++k) s = fmaf(wc[co * 9 + k], xp[k], s);
            acc[co] = s;
        }
#pragma unroll
        for (int k = 0; k < 9; ++k) xp[k] = xq[k] * msk9[k];
    }

#pragma unroll
    for (int co = 0; co < 27; ++co) red[chunk][lane][co] = acc[co];
    __syncthreads();

    if (tid < 64) {
        float s[27];
#pragma unroll
        for (int co = 0; co < 27; ++co)
            s[co] = red[0][lane][co] + red[1][lane][co]
                  + red[2][lane][co] + red[3][lane][co];
        int base = ((b * 9) * HO + h) * WO + w;
#pragma unroll
        for (int k = 0; k < 9; ++k) {
            float2v pp;
            pp.x = s[2 * k] + b_off[2 * k] + (float)(k / 3) + (float)h2;      // py
            pp.y = s[2 * k + 1] + b_off[2 * k + 1] + (float)(k % 3) + (float)wm1; // px
            pypx[base + k * HO * WO] = pp;
            m_out[base + k * HO * WO] =
                1.0f / (1.0f + __expf(-(s[18 + k] + b_msk[k])));
        }
    }
}

// ---------------------------------------------------------------------------
// Kernel 2: deformable sampling + MFMA matvec. Pos-tile = 32 (2048 blocks,
// 8/CU candidate). Gather: thread = (pos=tid&31, 8 ch = (tid>>5)*8); per
// (tap, channel) ONE 8B paired-corner load per row (border select folded
// into bilinear coeffs). Double-buffered S, single barrier per tap, tap k+1
// loads issued before tap k MFMAs. XCD swizzle b=bx&7.
// ---------------------------------------------------------------------------
__global__ __launch_bounds__(256) void dconv_mfma(
    const float* __restrict__ x,
    const float2v* __restrict__ pypx, const float* __restrict__ m_in,
    const __hip_bfloat16* __restrict__ W2,
    float* __restrict__ out)
{
    __shared__ __align__(16) __hip_bfloat16 S[2][32][64];  // 8 KB

    int tid = threadIdx.x;
    int lane = tid & 63;
    int wv = tid >> 6;

    int bx = blockIdx.x;               // 2048 blocks
    int b = bx & 7;
    int rest = bx >> 3;                // 256 = 64 h * 4 w-quarters
    int h = rest >> 2;
    int w0 = (rest & 3) * 32;

    int gpos = tid & 31;
    int cg = tid >> 5;                 // 0..7 -> channels cg*8..+8
    const int m16 = lane & 15;
    const int q = lane >> 4;

    floatx4 acc[2];
    acc[0] = (floatx4){0.f, 0.f, 0.f, 0.f};
    acc[1] = (floatx4){0.f, 0.f, 0.f, 0.f};

    const float* xg = x + (size_t)b * (CC * HW) + (size_t)cg * 8 * HW;
    int pidx = ((b * 9) * HO + h) * WO + w0 + gpos;

    float2a P[8], Q[8];
    float cxA, cyA, cxB, cyB;

    // issue gathers for one tap (loads left in flight in P/Q)
    auto issue = [&](float2v pp, float mk) {
        float py = pp.x, px = pp.y;
        float y0f = floorf(py), x0f = floorf(px);
        float dy = py - y0f, dx = px - x0f;
        int y0 = (int)y0f, x0 = (int)x0f;
        int y1 = y0 + 1, x1 = x0 + 1;
        bool vy0 = (unsigned)y0 < (unsigned)HH;
        bool vy1 = (unsigned)y1 < (unsigned)HH;
        bool vx0 = (unsigned)x0 < (unsigned)WW;
        bool vx1 = (unsigned)x1 < (unsigned)WW;
        float w00 = (1.0f - dy) * (1.0f - dx) * ((vy0 && vx0) ? mk : 0.0f);
        float w01 = (1.0f - dy) * dx          * ((vy0 && vx1) ? mk : 0.0f);
        float w10 = dy * (1.0f - dx)          * ((vy1 && vx0) ? mk : 0.0f);
        float w11 = dy * dx                   * ((vy1 && vx1) ? mk : 0.0f);
        int xbase = min(max(x0, 0), WW - 2);
        bool s0 = x0 > xbase;          // corner x0 sits at pair.y (only x0=127)
        bool s1 = x1 > xbase;          // corner x1 at pair.y (normal case)
        cxA = (s0 ? 0.f : w00) + (s1 ? 0.f : w01);
        cyA = (s0 ? w00 : 0.f) + (s1 ? w01 : 0.f);
        cxB = (s0 ? 0.f : w10) + (s1 ? 0.f : w11);
        cyB = (s0 ? w10 : 0.f) + (s1 ? w11 : 0.f);
        int yc0 = min(max(y0, 0), HH - 1);
        int yc1 = min(max(y1, 0), HH - 1);
        int r0 = yc0 * WW + xbase, r1 = yc1 * WW + xbase;
#pragma unroll
        for (int j = 0; j < 8; ++j) {
            P[j] = *(const float2a*)(xg + (size_t)j * HW + r0);
            Q[j] = *(const float2a*)(xg + (size_t)j * HW + r1);
        }
    };

    auto combine_store = [&](int buf) {
        short8 sv;
#pragma unroll
        for (int j = 0; j < 8; ++j) {
            float gv = cxA * P[j].x + cyA * P[j].y
                     + cxB * Q[j].x + cyB * Q[j].y;
            BfBits u; u.h = __float2bfloat16(gv);
            sv[j] = u.s;
        }
        *(short8*)&S[buf][gpos][(cg ^ (gpos & 7)) * 8] = sv;
    };

    {
        float2v pp = pypx[pidx];
        float mk = m_in[pidx];
        issue(pp, mk);
        combine_store(0);
    }

    for (int k = 0; k < 9; ++k) {
        __syncthreads();               // S[k&1] ready for all waves
        if (k < 8) {
            float2v pp = pypx[pidx + (k + 1) * (HO * WO)];
            float mk = m_in[pidx + (k + 1) * (HO * WO)];
            issue(pp, mk);             // loads in flight during MFMA phase
        }
        // ---- MFMA phase on S[k&1] ----
        {
            const __hip_bfloat16* wk =
                W2 + ((size_t)(k * OC) + wv * 16 + m16) * CC + q * 8;
            int buf = k & 1;
#pragma unroll
            for (int s = 0; s < 2; ++s) {
                short8 af = *(const short8*)(wk + s * 32);
                int cb = ((q + 4 * s) ^ (m16 & 7)) * 8;
                short8 bf0 = *(const short8*)&S[buf][m16][cb];
                short8 bf1 = *(const short8*)&S[buf][16 + m16][cb];
                acc[0] = __builtin_amdgcn_mfma_f32_16x16x32_bf16(af, bf0, acc[0], 0, 0, 0);
                acc[1] = __builtin_amdgcn_mfma_f32_16x16x32_bf16(af, bf1, acc[1], 0, 0, 0);
            }
        }
        if (k < 8) combine_store((k + 1) & 1);
    }

    // epilogue: C/D col=lane&15 (pos), row=(lane>>4)*4+reg (o)
#pragma unroll
    for (int nt = 0; nt < 2; ++nt) {
#pragma unroll
        for (int r = 0; r < 4; ++r) {
            int o = wv * 16 + q * 4 + r;
            out[(((size_t)b * OC + o) * HO + h) * WO + w0 + nt * 16 + m16]
                = acc[nt][r];
        }
    }
}

// ---------------------------------------------------------------------------
extern "C" void kernel_launch(void* const* d_in, const int* in_sizes, int n_in,
                              void* d_out, int out_size, void* d_ws, size_t ws_size,
                              hipStream_t stream)
{
    const float* x      = (const float*)d_in[0];
    const float* w_off  = (const float*)d_in[1];
    const float* b_off  = (const float*)d_in[2];
    const float* w_msk  = (const float*)d_in[3];
    const float* b_msk  = (const float*)d_in[4];
    const float* w_conv = (const float*)d_in[5];
    float* out = (float*)d_out;

    float2v* pypx = (float2v*)d_ws;                       // NPM float2
    float* m  = (float*)(pypx + NPM);                     // NPM floats
    __hip_bfloat16* W2 = (__hip_bfloat16*)(m + NPM);      // 36864 bf16
    float* w3 = (float*)(W2 + 9 * OC * CC);               // 16384 floats

    make_w3<<<dim3(61), dim3(256), 0, stream>>>(w_off, w_msk, w3);
    make_w2<<<dim3(144), dim3(256), 0, stream>>>(w_conv, W2);
    om_conv<<<dim3(1024), dim3(256), 0, stream>>>(x, w3, b_off, b_msk, pypx, m);
    dconv_mfma<<<dim3(2048), dim3(256), 0, stream>>>(x, pypx, m, W2, out);
}